// Round 3
// baseline (750.506 us; speedup 1.0000x reference)
//
#include <hip/hip_runtime.h>

#define NUM_ITEM 500000
#define EMBED_DIM 64
#define PAD 8

typedef float f4_native __attribute__((ext_vector_type(4)));

// ---------------- padded-CSR pipeline ----------------

// Fused histogram + scatter: slot = old count. One pass over edges.
// PAD=8: pad (16 MB) + cnt (2 MB) fit aggregate L2 -> the ~4 writes per
// bucket line coalesce in L2 instead of each evicting a 64B line.
__global__ __launch_bounds__(256) void scatter_pad(
    const int* __restrict__ edge_src, const int* __restrict__ edge_dst,
    int num_edges, int* __restrict__ cnt, int* __restrict__ pad,
    int* __restrict__ ovf, int* __restrict__ ovf_n, int ovf_cap)
{
    int e = blockIdx.x * 256 + threadIdx.x;
    if (e >= num_edges) return;
    int d = edge_dst[e];
    int s = edge_src[e];
    int slot = atomicAdd(&cnt[d], 1);
    if (slot < PAD) {
        pad[(size_t)d * PAD + slot] = s;
    } else {
        int o = atomicAdd(ovf_n, 1);
        if (o < ovf_cap) { ovf[2 * o] = d; ovf[2 * o + 1] = s; }
    }
}

// One 64-lane wave per item. lane = 16*g + q:
//   g = edge group (0..3), q = dim quad (0..15, covers dims 4q..4q+3).
// Two float4 gathers cover all 8 pad slots (4 rows per load instruction),
// then an 8-op shfl_xor reduce across groups. 4x fewer load instrs and
// ~4x less address VALU than the scalar version; same bytes in flight.
__global__ __launch_bounds__(256) void gather_pad(
    const float* __restrict__ user_embed, const int* __restrict__ pad,
    const int* __restrict__ cnt, float* __restrict__ out, int n_items)
{
    int item = blockIdx.x * 4 + (threadIdx.x >> 6);
    int lane = threadIdx.x & 63;
    if (item >= n_items) return;
    int g = lane >> 4;
    int q = lane & 15;

    const int* p = pad + (size_t)item * PAD;
    int c = cnt[item];                        // wave-uniform
    int4 i0 = *(const int4*)p;                // all 8 slot indices (broadcast)
    int4 i1 = *(const int4*)(p + 4);

    // select this group's edge for round 0 / round 1 (cndmask chain)
    int s0 = (g == 0) ? i0.x : (g == 1) ? i0.y : (g == 2) ? i0.z : i0.w;
    int s1 = (g == 0) ? i1.x : (g == 1) ? i1.y : (g == 2) ? i1.z : i1.w;
    bool v0 = (g < c);
    bool v1 = (4 + g < c);
    s0 = v0 ? s0 : 0;                         // clamp -> safe, L1-hot row 0
    s1 = v1 ? s1 : 0;

    const float* r0 = user_embed + ((size_t)(unsigned)s0 << 6) + (q << 2);
    const float* r1 = user_embed + ((size_t)(unsigned)s1 << 6) + (q << 2);
    float4 a = *(const float4*)r0;            // two independent 4-row gathers
    float4 b = *(const float4*)r1;

    float4 acc;
    acc.x = (v0 ? a.x : 0.f) + (v1 ? b.x : 0.f);
    acc.y = (v0 ? a.y : 0.f) + (v1 ? b.y : 0.f);
    acc.z = (v0 ? a.z : 0.f) + (v1 ? b.z : 0.f);
    acc.w = (v0 ? a.w : 0.f) + (v1 ? b.w : 0.f);

    // reduce across the 4 edge groups (lanes i, i+16, i+32, i+48)
    acc.x += __shfl_xor(acc.x, 16, 64);
    acc.y += __shfl_xor(acc.y, 16, 64);
    acc.z += __shfl_xor(acc.z, 16, 64);
    acc.w += __shfl_xor(acc.w, 16, 64);
    acc.x += __shfl_xor(acc.x, 32, 64);
    acc.y += __shfl_xor(acc.y, 32, 64);
    acc.z += __shfl_xor(acc.z, 32, 64);
    acc.w += __shfl_xor(acc.w, 32, 64);

    float inv = 1.0f / ((c > 0) ? (float)c : 1.0f);
    acc.x *= inv; acc.y *= inv; acc.z *= inv; acc.w *= inv;

    if (g == 0) {
        // 16 lanes x 16B = coalesced 256B; nontemporal: don't let the
        // 128 MB output stream evict pad/cnt + hot user rows from L2.
        f4_native nv;
        nv.x = acc.x; nv.y = acc.y; nv.z = acc.z; nv.w = acc.w;
        __builtin_nontemporal_store(
            nv, (f4_native*)(out + ((size_t)item << 6) + (q << 2)));
    }
}

// Exact handling of cnt > PAD items (~2% of items at mean degree 4).
// out already holds sum(first PAD)/cnt; add row/cnt per overflow edge.
__global__ __launch_bounds__(256) void fixup_overflow(
    const float* __restrict__ user_embed, const int* __restrict__ ovf,
    const int* __restrict__ ovf_n, const int* __restrict__ cnt,
    float* __restrict__ out, int ovf_cap)
{
    int n = *ovf_n;
    if (n > ovf_cap) n = ovf_cap;
    int wave = blockIdx.x * 4 + (threadIdx.x >> 6);
    int lane = threadIdx.x & 63;
    int nwaves = gridDim.x * 4;
    for (int i = wave; i < n; i += nwaves) {
        int d = ovf[2 * i];
        int s = ovf[2 * i + 1];
        float v = user_embed[(size_t)s * EMBED_DIM + lane] / (float)cnt[d];
        atomicAdd(&out[(size_t)d * EMBED_DIM + lane], v);
    }
}

// ---------------- tier-2: exact CSR pipeline ----------------

__global__ __launch_bounds__(256) void histogram_dst(
    const int* __restrict__ edge_dst, int num_edges, int* __restrict__ counts)
{
    int e = blockIdx.x * blockDim.x + threadIdx.x;
    if (e >= num_edges) return;
    atomicAdd(&counts[edge_dst[e]], 1);
}

__global__ __launch_bounds__(256) void block_sums(
    const int* __restrict__ counts, int n, int* __restrict__ partials)
{
    __shared__ int red[256];
    int i = blockIdx.x * 256 + threadIdx.x;
    red[threadIdx.x] = (i < n) ? counts[i] : 0;
    __syncthreads();
    for (int s = 128; s > 0; s >>= 1) {
        if (threadIdx.x < (unsigned)s) red[threadIdx.x] += red[threadIdx.x + s];
        __syncthreads();
    }
    if (threadIdx.x == 0) partials[blockIdx.x] = red[0];
}

__global__ __launch_bounds__(256) void scan_partials(int* __restrict__ partials, int nb)
{
    __shared__ int tmp[256];
    __shared__ int carry_s;
    if (threadIdx.x == 0) carry_s = 0;
    __syncthreads();
    for (int base = 0; base < nb; base += 256) {
        int i = base + threadIdx.x;
        int v = (i < nb) ? partials[i] : 0;
        tmp[threadIdx.x] = v;
        __syncthreads();
        for (int off = 1; off < 256; off <<= 1) {
            int t = (threadIdx.x >= (unsigned)off) ? tmp[threadIdx.x - off] : 0;
            __syncthreads();
            tmp[threadIdx.x] += t;
            __syncthreads();
        }
        int incl = tmp[threadIdx.x];
        int c = carry_s;
        if (i < nb) partials[i] = incl - v + c;
        __syncthreads();
        if (threadIdx.x == 255) carry_s = c + tmp[255];
        __syncthreads();
    }
}

__global__ __launch_bounds__(256) void make_offsets(
    const int* __restrict__ counts, const int* __restrict__ partials, int n,
    int* __restrict__ offsets, int* __restrict__ cursor)
{
    __shared__ int tmp[256];
    int i = blockIdx.x * 256 + threadIdx.x;
    int v = (i < n) ? counts[i] : 0;
    tmp[threadIdx.x] = v;
    __syncthreads();
    for (int off = 1; off < 256; off <<= 1) {
        int t = (threadIdx.x >= (unsigned)off) ? tmp[threadIdx.x - off] : 0;
        __syncthreads();
        tmp[threadIdx.x] += t;
        __syncthreads();
    }
    int excl = tmp[threadIdx.x] - v + partials[blockIdx.x];
    if (i < n) { offsets[i] = excl; cursor[i] = excl; }
}

__global__ __launch_bounds__(256) void scatter_csr(
    const int* __restrict__ edge_src, const int* __restrict__ edge_dst,
    int num_edges, int* __restrict__ cursor, int* __restrict__ csr_src)
{
    int e = blockIdx.x * blockDim.x + threadIdx.x;
    if (e >= num_edges) return;
    int d = edge_dst[e];
    int pos = atomicAdd(&cursor[d], 1);
    csr_src[pos] = edge_src[e];
}

__global__ __launch_bounds__(256) void gather_mean(
    const float* __restrict__ user_embed, const int* __restrict__ csr_src,
    const int* __restrict__ offsets, const int* __restrict__ counts,
    float* __restrict__ out, int n_items)
{
    int item = blockIdx.x * 4 + (threadIdx.x >> 6);
    int lane = threadIdx.x & 63;
    if (item >= n_items) return;
    int off = offsets[item];
    int cnt = counts[item];
    float sum = 0.f;
    for (int e = 0; e < cnt; ++e) {
        int s = csr_src[off + e];
        sum += user_embed[(size_t)s * EMBED_DIM + lane];
    }
    float denom = (cnt > 0) ? (float)cnt : 1.0f;
    out[(size_t)item * EMBED_DIM + lane] = sum / denom;
}

// ---------------- tier-3: atomic fallback ----------------

__global__ __launch_bounds__(256) void scatter_mean_accum(
    const float* __restrict__ user_embed,
    const int* __restrict__ edge_src,
    const int* __restrict__ edge_dst,
    float* __restrict__ sums, float* __restrict__ counts, int num_edges)
{
    const int edge = blockIdx.x * (blockDim.x >> 6) + (threadIdx.x >> 6);
    const int lane = threadIdx.x & 63;
    if (edge >= num_edges) return;
    const int s = edge_src[edge];
    const int d = edge_dst[edge];
    atomicAdd(&sums[(size_t)d * EMBED_DIM + lane],
              user_embed[(size_t)s * EMBED_DIM + lane]);
    if (lane == 0) atomicAdd(&counts[d], 1.0f);
}

__global__ __launch_bounds__(256) void divide_by_count(
    float* __restrict__ out, const float* __restrict__ counts, int n)
{
    const int idx = blockIdx.x * blockDim.x + threadIdx.x;
    if (idx >= n) return;
    out[idx] = out[idx] / fmaxf(counts[idx >> 6], 1.0f);
}

// ---------------- launcher ----------------

extern "C" void kernel_launch(void* const* d_in, const int* in_sizes, int n_in,
                              void* d_out, int out_size, void* d_ws, size_t ws_size,
                              hipStream_t stream)
{
    const float* user_embed = (const float*)d_in[0];
    const int* edge_src = (const int*)d_in[2];
    const int* edge_dst = (const int*)d_in[3];
    const int num_edges = in_sizes[2];
    float* out = (float*)d_out;

    const int eb = (num_edges + 255) / 256;

    // ---- tier 1: padded CSR ----
    // ws layout: ovf_n(64B) | cnt (2MB) | pad (NUM_ITEM*PAD*4 = 16MB) | ovf (2*cap*4)
    const size_t hdr_b = 64;
    const size_t cnt_b = (size_t)NUM_ITEM * 4;
    const size_t pad_b = (size_t)NUM_ITEM * PAD * 4;
    const size_t fixed = hdr_b + cnt_b + pad_b;
    long long cap_ll = ((long long)ws_size - (long long)fixed) / 8;
    if (cap_ll > num_edges) cap_ll = num_edges;
    const int min_cap = (num_edges < 65536) ? num_edges : 65536;

    if (cap_ll >= min_cap) {
        char* ws = (char*)d_ws;
        int* ovf_n = (int*)ws;
        int* cnt   = (int*)(ws + hdr_b);
        int* pad   = (int*)(ws + hdr_b + cnt_b);
        int* ovf   = (int*)(ws + fixed);
        const int ovf_cap = (int)cap_ll;

        (void)hipMemsetAsync(d_ws, 0, hdr_b + cnt_b, stream);   // ovf_n + cnt
        scatter_pad<<<eb, 256, 0, stream>>>(edge_src, edge_dst, num_edges,
                                            cnt, pad, ovf, ovf_n, ovf_cap);
        gather_pad<<<(NUM_ITEM + 3) / 4, 256, 0, stream>>>(
            user_embed, pad, cnt, out, NUM_ITEM);
        fixup_overflow<<<512, 256, 0, stream>>>(user_embed, ovf, ovf_n, cnt,
                                                out, ovf_cap);
        return;
    }

    // ---- tier 2: exact CSR pipeline ----
    const int NB = (NUM_ITEM + 255) / 256;
    const size_t counts_b   = (size_t)NUM_ITEM * 4;
    const size_t offsets_b  = (size_t)NUM_ITEM * 4;
    const size_t cursor_b   = (size_t)NUM_ITEM * 4;
    const size_t partials_b = 2048 * 4;
    const size_t csr_b      = (size_t)num_edges * 4;
    const size_t needed = counts_b + offsets_b + cursor_b + partials_b + csr_b;

    if (ws_size >= needed) {
        char* ws = (char*)d_ws;
        int* counts   = (int*)ws;                         ws += counts_b;
        int* offsets  = (int*)ws;                         ws += offsets_b;
        int* cursor   = (int*)ws;                         ws += cursor_b;
        int* partials = (int*)ws;                         ws += partials_b;
        int* csr_src  = (int*)ws;

        (void)hipMemsetAsync(counts, 0, counts_b, stream);
        histogram_dst<<<eb, 256, 0, stream>>>(edge_dst, num_edges, counts);
        block_sums<<<NB, 256, 0, stream>>>(counts, NUM_ITEM, partials);
        scan_partials<<<1, 256, 0, stream>>>(partials, NB);
        make_offsets<<<NB, 256, 0, stream>>>(counts, partials, NUM_ITEM, offsets, cursor);
        scatter_csr<<<eb, 256, 0, stream>>>(edge_src, edge_dst, num_edges, cursor, csr_src);
        gather_mean<<<(NUM_ITEM + 3) / 4, 256, 0, stream>>>(
            user_embed, csr_src, offsets, counts, out, NUM_ITEM);
    } else {
        // ---- tier 3: atomic scatter ----
        float* counts = (float*)d_ws;
        (void)hipMemsetAsync(d_out, 0, (size_t)NUM_ITEM * EMBED_DIM * sizeof(float), stream);
        (void)hipMemsetAsync(d_ws, 0, (size_t)NUM_ITEM * sizeof(float), stream);
        const int blocks = (num_edges + 3) / 4;
        scatter_mean_accum<<<blocks, 256, 0, stream>>>(
            user_embed, edge_src, edge_dst, out, counts, num_edges);
        const int n = NUM_ITEM * EMBED_DIM;
        divide_by_count<<<(n + 255) / 256, 256, 0, stream>>>(out, counts, n);
    }
}